// Round 1
// baseline (2328.192 us; speedup 1.0000x reference)
//
#include <hip/hip_runtime.h>
#include <math.h>

#define NPG 75
#define KDIM 5

__device__ __forceinline__ float eluf(float v){ return v > 0.f ? v : expf(v) - 1.f; }

// order-preserving float <-> uint encoding (for atomicMax-based segment max)
__device__ __forceinline__ unsigned fenc(float f){
    unsigned u = __float_as_uint(f);
    return (u & 0x80000000u) ? ~u : (u | 0x80000000u);
}
__device__ __forceinline__ float fdec(unsigned u){
    return (u & 0x80000000u) ? __uint_as_float(u & 0x7FFFFFFFu) : __uint_as_float(~u);
}

// spline basis: pseudo = cart/(2*amax)+0.5, clip[0,1], *4; 4 corner weights + kernel ids
__device__ __forceinline__ void spline2(float c0, float c1, float am, int* kks, float* wsp){
    float denom = 2.f * fmaxf(am, 1e-12f);
    float p0 = c0 / denom + 0.5f;
    float p1 = c1 / denom + 0.5f;
    p0 = fminf(fmaxf(p0, 0.f), 1.f) * 4.f;
    p1 = fminf(fmaxf(p1, 0.f), 1.f) * 4.f;
    float b0 = fminf(floorf(p0), 3.f);
    float b1 = fminf(floorf(p1), 3.f);
    float f0 = p0 - b0, f1 = p1 - b1;
    int i0 = (int)b0, i1 = (int)b1;
    wsp[0] = (1.f - f0) * (1.f - f1); kks[0] = i0     + KDIM *  i1;
    wsp[1] =        f0  * (1.f - f1); kks[1] = i0 + 1 + KDIM *  i1;
    wsp[2] = (1.f - f0) *        f1 ; kks[2] = i0     + KDIM * (i1 + 1);
    wsp[3] =        f0  *        f1 ; kks[3] = i0 + 1 + KDIM * (i1 + 1);
}

// ---------------- amax over |pos[src]-pos[dst]| (all edges) ----------------
__global__ void amax0_k(const float* __restrict__ pos, const int* __restrict__ src,
                        const int* __restrict__ dst, int E, unsigned* __restrict__ amax){
    int e = blockIdx.x * 256 + threadIdx.x;
    float cand = 0.f;
    if (e < E){
        int s = src[e], d = dst[e];
        float c0 = pos[s*2]   - pos[d*2];
        float c1 = pos[s*2+1] - pos[d*2+1];
        cand = fmaxf(fabsf(c0), fabsf(c1));
    }
    __shared__ float sm[256];
    sm[threadIdx.x] = cand; __syncthreads();
    for (int o = 128; o > 0; o >>= 1){
        if (threadIdx.x < o) sm[threadIdx.x] = fmaxf(sm[threadIdx.x], sm[threadIdx.x + o]);
        __syncthreads();
    }
    if (threadIdx.x == 0 && sm[0] > 0.f) atomicMax(amax, __float_as_uint(sm[0]));
}

// ---------------- conv1: aggregate (Fin=1) ----------------
__global__ void conv1_edge_k(const float* __restrict__ x, const float* __restrict__ pos,
                             const int* __restrict__ src, const int* __restrict__ dst, int E,
                             const unsigned* __restrict__ amaxp,
                             float* __restrict__ acc, float* __restrict__ deg){
    int e = blockIdx.x * 256 + threadIdx.x;
    if (e >= E) return;
    int s = src[e], d = dst[e];
    float am = __uint_as_float(*amaxp);
    float c0 = pos[s*2]   - pos[d*2];
    float c1 = pos[s*2+1] - pos[d*2+1];
    int kks[4]; float wsp[4];
    spline2(c0, c1, am, kks, wsp);
    float xv = x[s];
    #pragma unroll
    for (int c = 0; c < 4; c++) atomicAdd(&acc[(size_t)d*25 + kks[c]], wsp[c] * xv);
    atomicAdd(&deg[d], 1.f);
}

__global__ void conv1_node_k(const float* __restrict__ acc, const float* __restrict__ deg,
                             const float* __restrict__ x, const float* __restrict__ W1,
                             const float* __restrict__ r1, const float* __restrict__ b1,
                             int N, float* __restrict__ out){
    int gid = blockIdx.x * 256 + threadIdx.x;
    int i = gid >> 5, o = gid & 31;
    if (i >= N) return;
    float sum = 0.f;
    #pragma unroll
    for (int k = 0; k < 25; k++) sum += acc[(size_t)i*25 + k] * W1[k*32 + o];
    float v = sum / fmaxf(deg[i], 1.f) + x[i] * r1[o] + b1[o];
    out[(size_t)i*32 + o] = eluf(v);
}

// ---------------- generic pooling ----------------
template<int LOGF>
__global__ void pool_node_k(const float* __restrict__ x, const float* __restrict__ pos,
                            const float* __restrict__ valid, int n, float size, int G, int npg,
                            int* __restrict__ cl, unsigned* __restrict__ pxenc,
                            float* __restrict__ cnt, float* __restrict__ possum){
    const int F = 1 << LOGF;
    int gid = blockIdx.x * 256 + threadIdx.x;
    int i = gid >> LOGF, f = gid & (F - 1);
    if (i >= n) return;
    float p0 = pos[i*2], p1 = pos[i*2+1];
    int c0 = min(max((int)floorf(p0 / size), 0), G - 1);
    int c1 = min(max((int)floorf(p1 / size), 0), G - 1);
    int b = i / npg;
    int c = b * G * G + c1 * G + c0;
    if (f == 0) cl[i] = c;
    float vld = valid ? valid[i] : 1.f;
    if (vld > 0.f){
        atomicMax(&pxenc[(size_t)c*F + f], fenc(x[(size_t)i*F + f]));
        if (f == 0){
            atomicAdd(&cnt[c], 1.f);
            atomicAdd(&possum[c*2],     p0);
            atomicAdd(&possum[c*2 + 1], p1);
        }
    }
}

template<int LOGF>
__global__ void pool_fin_k(unsigned* __restrict__ pxenc, const float* __restrict__ cnt,
                           float* __restrict__ possum, float* __restrict__ sval, int S){
    const int F = 1 << LOGF;
    int gid = blockIdx.x * 256 + threadIdx.x;
    int s = gid >> LOGF, f = gid & (F - 1);
    if (s >= S) return;
    float c = cnt[s];
    float v = (c > 0.f) ? fdec(pxenc[(size_t)s*F + f]) : 0.f;
    ((float*)pxenc)[(size_t)s*F + f] = v;
    if (f == 0){
        float m = fmaxf(c, 1.f);
        possum[s*2]     /= m;
        possum[s*2 + 1] /= m;
        sval[s] = (c > 0.f) ? 1.f : 0.f;
    }
}

// ---------------- edge remap + dedup ----------------
__global__ void dedup_a_k(const int* __restrict__ esrc_in, const int* __restrict__ edst_in,
                          const int* __restrict__ clmap, const unsigned char* __restrict__ maskin,
                          int E, int GG, int* __restrict__ esrc_out, int* __restrict__ edst_out,
                          unsigned* __restrict__ pairmark){
    int e = blockIdx.x * 256 + threadIdx.x;
    if (e >= E) return;
    int a = clmap[esrc_in[e]], b = clmap[edst_in[e]];
    esrc_out[e] = a; edst_out[e] = b;
    bool m = (maskin ? (maskin[e] != 0) : true) && (a != b);
    if (m){
        int g = a / GG;
        unsigned key = (unsigned)((size_t)g * GG * GG + (a - g * GG) * GG + (b - g * GG));
        atomicMin(&pairmark[key], (unsigned)e);
    }
}

__global__ void dedup_b_k(const int* __restrict__ esrc, const int* __restrict__ edst,
                          const unsigned char* __restrict__ maskin, const unsigned* __restrict__ pairmark,
                          const float* __restrict__ ppos, int E, int GG,
                          unsigned char* __restrict__ kf, float* __restrict__ deg,
                          unsigned* __restrict__ amax){
    int e = blockIdx.x * 256 + threadIdx.x;
    float cand = 0.f;
    if (e < E){
        int a = esrc[e], b = edst[e];
        bool m = (maskin ? (maskin[e] != 0) : true) && (a != b);
        bool kept = false;
        if (m){
            int g = a / GG;
            unsigned key = (unsigned)((size_t)g * GG * GG + (a - g * GG) * GG + (b - g * GG));
            kept = (pairmark[key] == (unsigned)e);
        }
        kf[e] = kept ? 1 : 0;
        if (kept){
            float c0 = ppos[a*2]   - ppos[b*2];
            float c1 = ppos[a*2+1] - ppos[b*2+1];
            cand = fmaxf(fabsf(c0), fabsf(c1));
            atomicAdd(&deg[b], 1.f);
        }
    }
    __shared__ float sm[256];
    sm[threadIdx.x] = cand; __syncthreads();
    for (int o = 128; o > 0; o >>= 1){
        if (threadIdx.x < o) sm[threadIdx.x] = fmaxf(sm[threadIdx.x], sm[threadIdx.x + o]);
        __syncthreads();
    }
    if (threadIdx.x == 0 && sm[0] > 0.f) atomicMax(amax, __float_as_uint(sm[0]));
}

// ---------------- conv2/conv3: transform-then-aggregate ----------------
template<int FIN>
__global__ void conv_edge_k(const float* __restrict__ x, const float* __restrict__ ppos,
                            const int* __restrict__ esrc, const int* __restrict__ edst,
                            const unsigned char* __restrict__ kf, const float* __restrict__ W,
                            const unsigned* __restrict__ amaxp, int E,
                            float* __restrict__ outacc){
    int gid = blockIdx.x * 256 + threadIdx.x;
    int e = gid >> 6, o = gid & 63;
    if (e >= E) return;
    if (!kf[e]) return;
    int a = esrc[e], b = edst[e];
    float am = __uint_as_float(*amaxp);
    float c0 = ppos[a*2]   - ppos[b*2];
    float c1 = ppos[a*2+1] - ppos[b*2+1];
    int kks[4]; float wsp[4];
    spline2(c0, c1, am, kks, wsp);
    const float* xr = x + (size_t)a * FIN;
    float acc = 0.f;
    #pragma unroll
    for (int c = 0; c < 4; c++){
        const float* Wk = W + ((size_t)kks[c] * FIN) * 64 + o;
        float dot = 0.f;
        #pragma unroll
        for (int f = 0; f < FIN; f++) dot += xr[f] * Wk[(size_t)f * 64];
        acc += wsp[c] * dot;
    }
    atomicAdd(&outacc[(size_t)b*64 + o], acc);
}

template<int FIN>
__global__ void conv_node_k(float* __restrict__ io, const float* __restrict__ deg,
                            const float* __restrict__ x, const float* __restrict__ root,
                            const float* __restrict__ bias, int n){
    int gid = blockIdx.x * 256 + threadIdx.x;
    int i = gid >> 6, o = gid & 63;
    if (i >= n) return;
    float v = io[(size_t)i*64 + o] / fmaxf(deg[i], 1.f);
    const float* xr = x + (size_t)i * FIN;
    float r = 0.f;
    #pragma unroll
    for (int f = 0; f < FIN; f++) r += xr[f] * root[(size_t)f*64 + o];
    io[(size_t)i*64 + o] = eluf(v + r + bias[o]);
}

// ---------------- MLP head + log_softmax ----------------
__global__ void mlp_k(const float* __restrict__ px, const float* __restrict__ fw1,
                      const float* __restrict__ fb1, const float* __restrict__ fw2,
                      const float* __restrict__ fb2, float* __restrict__ out){
    __shared__ float xr[256];
    __shared__ float h[128];
    __shared__ float lg[10];
    __shared__ float lse;
    int g = blockIdx.x, t = threadIdx.x;
    xr[t]       = px[(size_t)g*256 + t];
    xr[t + 128] = px[(size_t)g*256 + 128 + t];
    __syncthreads();
    float s = fb1[t];
    const float* wrow = fw1 + (size_t)t * 256;
    #pragma unroll 8
    for (int i = 0; i < 256; i++) s += xr[i] * wrow[i];
    h[t] = eluf(s);
    __syncthreads();
    if (t < 10){
        float s2 = fb2[t];
        const float* w2 = fw2 + (size_t)t * 128;
        for (int j = 0; j < 128; j++) s2 += h[j] * w2[j];
        lg[t] = s2;
    }
    __syncthreads();
    if (t == 0){
        float m = lg[0];
        for (int c = 1; c < 10; c++) m = fmaxf(m, lg[c]);
        float se = 0.f;
        for (int c = 0; c < 10; c++) se += expf(lg[c] - m);
        lse = m + logf(se);
    }
    __syncthreads();
    if (t < 10) out[(size_t)g*10 + t] = lg[t] - lse;
}

extern "C" void kernel_launch(void* const* d_in, const int* in_sizes, int n_in,
                              void* d_out, int out_size, void* d_ws, size_t ws_size,
                              hipStream_t stream) {
    const float* x   = (const float*)d_in[0];
    const float* pos = (const float*)d_in[1];
    const int*   src = (const int*)d_in[2];
    const int*   dst = (const int*)d_in[3];
    const float* W1  = (const float*)d_in[4];
    const float* r1  = (const float*)d_in[5];
    const float* b1  = (const float*)d_in[6];
    const float* W2  = (const float*)d_in[7];
    const float* r2  = (const float*)d_in[8];
    const float* b2  = (const float*)d_in[9];
    const float* W3  = (const float*)d_in[10];
    const float* r3  = (const float*)d_in[11];
    const float* b3  = (const float*)d_in[12];
    const float* fw1 = (const float*)d_in[13];
    const float* fb1 = (const float*)d_in[14];
    const float* fw2 = (const float*)d_in[15];
    const float* fb2 = (const float*)d_in[16];
    float* out = (float*)d_out;

    const int N  = in_sizes[0];
    const int E  = in_sizes[2];
    const int B  = N / NPG;
    const int S1 = B * 36;
    const int S2 = B * 25;
    const int B4 = B * 4;

    float* w = (float*)d_ws;
    size_t off = 0;
    auto alloc = [&](size_t nelem){ size_t o = off; off += (nelem + 63) & ~(size_t)63; return o; };

    // zero-init region
    size_t o_scal = alloc(4);                 // amax0, amax1, amax2 (uint bits of nonneg floats)
    size_t o_acc1 = alloc((size_t)N * 25);
    size_t o_deg1 = alloc(N);
    size_t o_cnt1 = alloc(S1);
    size_t o_pp1  = alloc((size_t)S1 * 2);
    size_t o_px1  = alloc((size_t)S1 * 32);
    size_t o_deg2 = alloc(S1);
    size_t o_out2 = alloc((size_t)S1 * 64);
    size_t o_cnt2 = alloc(S2);
    size_t o_pp2  = alloc((size_t)S2 * 2);
    size_t o_px2  = alloc((size_t)S2 * 64);
    size_t o_deg3 = alloc(S2);
    size_t o_out3 = alloc((size_t)S2 * 64);
    size_t o_cnt3 = alloc(B4);
    size_t o_pp3  = alloc((size_t)B4 * 2);
    size_t o_px3  = alloc((size_t)B4 * 64);
    size_t zeroEnd = off;
    // 0xFF-init region (pair markers, atomicMin with UINT_MAX init)
    size_t o_pm1 = alloc((size_t)B * 36 * 36);
    size_t o_pm2 = alloc((size_t)B * 25 * 25);
    size_t ffEnd = off;
    // no-init region (fully written before read)
    size_t o_out1  = alloc((size_t)N * 32);
    size_t o_cl1   = alloc(N);
    size_t o_sv1   = alloc(S1);
    size_t o_es1   = alloc(E);
    size_t o_ed1   = alloc(E);
    size_t o_kf1   = alloc((E + 3) / 4);
    size_t o_cl2   = alloc(S1);
    size_t o_sv2   = alloc(S2);
    size_t o_es2   = alloc(E);
    size_t o_ed2   = alloc(E);
    size_t o_kf2   = alloc((E + 3) / 4);
    size_t o_cl3   = alloc(S2);
    size_t o_sv3   = alloc(B4);

    hipMemsetAsync(w, 0, zeroEnd * sizeof(float), stream);
    hipMemsetAsync((char*)d_ws + zeroEnd * sizeof(float), 0xFF, (ffEnd - zeroEnd) * sizeof(float), stream);

    unsigned* scal = (unsigned*)(w + o_scal);
    auto nb = [](long long t){ return (unsigned)((t + 255) / 256); };

    // stage 1: conv1 on original graph
    amax0_k<<<nb(E), 256, 0, stream>>>(pos, src, dst, E, scal + 0);
    conv1_edge_k<<<nb(E), 256, 0, stream>>>(x, pos, src, dst, E, scal + 0, w + o_acc1, w + o_deg1);
    conv1_node_k<<<nb((long long)N * 32), 256, 0, stream>>>(w + o_acc1, w + o_deg1, x, W1, r1, b1, N, w + o_out1);

    // pool 1 (size=5, G=6)
    pool_node_k<5><<<nb((long long)N * 32), 256, 0, stream>>>(
        w + o_out1, pos, nullptr, N, 5.f, 6, NPG,
        (int*)(w + o_cl1), (unsigned*)(w + o_px1), w + o_cnt1, w + o_pp1);
    pool_fin_k<5><<<nb((long long)S1 * 32), 256, 0, stream>>>(
        (unsigned*)(w + o_px1), w + o_cnt1, w + o_pp1, w + o_sv1, S1);
    dedup_a_k<<<nb(E), 256, 0, stream>>>(src, dst, (int*)(w + o_cl1), nullptr, E, 36,
                                         (int*)(w + o_es1), (int*)(w + o_ed1), (unsigned*)(w + o_pm1));
    dedup_b_k<<<nb(E), 256, 0, stream>>>((int*)(w + o_es1), (int*)(w + o_ed1), nullptr,
                                         (unsigned*)(w + o_pm1), w + o_pp1, E, 36,
                                         (unsigned char*)(w + o_kf1), w + o_deg2, scal + 1);

    // conv2 (Fin=32 -> 64) on S1 clusters
    conv_edge_k<32><<<nb((long long)E * 64), 256, 0, stream>>>(
        w + o_px1, w + o_pp1, (int*)(w + o_es1), (int*)(w + o_ed1),
        (unsigned char*)(w + o_kf1), W2, scal + 1, E, w + o_out2);
    conv_node_k<32><<<nb((long long)S1 * 64), 256, 0, stream>>>(
        w + o_out2, w + o_deg2, w + o_px1, r2, b2, S1);

    // pool 2 (size=7, G=5)
    pool_node_k<6><<<nb((long long)S1 * 64), 256, 0, stream>>>(
        w + o_out2, w + o_pp1, w + o_sv1, S1, 7.f, 5, 36,
        (int*)(w + o_cl2), (unsigned*)(w + o_px2), w + o_cnt2, w + o_pp2);
    pool_fin_k<6><<<nb((long long)S2 * 64), 256, 0, stream>>>(
        (unsigned*)(w + o_px2), w + o_cnt2, w + o_pp2, w + o_sv2, S2);
    dedup_a_k<<<nb(E), 256, 0, stream>>>((int*)(w + o_es1), (int*)(w + o_ed1), (int*)(w + o_cl2),
                                         (unsigned char*)(w + o_kf1), E, 25,
                                         (int*)(w + o_es2), (int*)(w + o_ed2), (unsigned*)(w + o_pm2));
    dedup_b_k<<<nb(E), 256, 0, stream>>>((int*)(w + o_es2), (int*)(w + o_ed2),
                                         (unsigned char*)(w + o_kf1), (unsigned*)(w + o_pm2),
                                         w + o_pp2, E, 25,
                                         (unsigned char*)(w + o_kf2), w + o_deg3, scal + 2);

    // conv3 (Fin=64 -> 64) on S2 clusters
    conv_edge_k<64><<<nb((long long)E * 64), 256, 0, stream>>>(
        w + o_px2, w + o_pp2, (int*)(w + o_es2), (int*)(w + o_ed2),
        (unsigned char*)(w + o_kf2), W3, scal + 2, E, w + o_out3);
    conv_node_k<64><<<nb((long long)S2 * 64), 256, 0, stream>>>(
        w + o_out3, w + o_deg3, w + o_px2, r3, b3, S2);

    // final max_pool_x (size=14, G=2) — reuse generic pooling; pos/cl/sval outputs unused
    pool_node_k<6><<<nb((long long)S2 * 64), 256, 0, stream>>>(
        w + o_out3, w + o_pp2, w + o_sv2, S2, 14.f, 2, 25,
        (int*)(w + o_cl3), (unsigned*)(w + o_px3), w + o_cnt3, w + o_pp3);
    pool_fin_k<6><<<nb((long long)B4 * 64), 256, 0, stream>>>(
        (unsigned*)(w + o_px3), w + o_cnt3, w + o_pp3, w + o_sv3, B4);

    // MLP head + log_softmax
    mlp_k<<<B, 128, 0, stream>>>(w + o_px3, fw1, fb1, fw2, fb2, out);
}

// Round 2
// 1472.872 us; speedup vs baseline: 1.5807x; 1.5807x over previous
//
#include <hip/hip_runtime.h>
#include <math.h>

#define NPG 75
#define KDIM 5

__device__ __forceinline__ float eluf(float v){ return v > 0.f ? v : expf(v) - 1.f; }

// order-preserving float <-> uint encoding (for atomicMax-based segment max)
__device__ __forceinline__ unsigned fenc(float f){
    unsigned u = __float_as_uint(f);
    return (u & 0x80000000u) ? ~u : (u | 0x80000000u);
}
__device__ __forceinline__ float fdec(unsigned u){
    return (u & 0x80000000u) ? __uint_as_float(u & 0x7FFFFFFFu) : __uint_as_float(~u);
}

// spline basis: pseudo = cart/(2*amax)+0.5, clip[0,1], *4; 4 corner weights + kernel ids
__device__ __forceinline__ void spline2(float c0, float c1, float am, int* kks, float* wsp){
    float denom = 2.f * fmaxf(am, 1e-12f);
    float p0 = c0 / denom + 0.5f;
    float p1 = c1 / denom + 0.5f;
    p0 = fminf(fmaxf(p0, 0.f), 1.f) * 4.f;
    p1 = fminf(fmaxf(p1, 0.f), 1.f) * 4.f;
    float b0 = fminf(floorf(p0), 3.f);
    float b1 = fminf(floorf(p1), 3.f);
    float f0 = p0 - b0, f1 = p1 - b1;
    int i0 = (int)b0, i1 = (int)b1;
    wsp[0] = (1.f - f0) * (1.f - f1); kks[0] = i0     + KDIM *  i1;
    wsp[1] =        f0  * (1.f - f1); kks[1] = i0 + 1 + KDIM *  i1;
    wsp[2] = (1.f - f0) *        f1 ; kks[2] = i0     + KDIM * (i1 + 1);
    wsp[3] =        f0  *        f1 ; kks[3] = i0 + 1 + KDIM * (i1 + 1);
}

// ---------------- amax over |pos[src]-pos[dst]| (all edges) ----------------
__global__ void amax0_k(const float* __restrict__ pos, const int* __restrict__ src,
                        const int* __restrict__ dst, int E, unsigned* __restrict__ amax){
    int e = blockIdx.x * 256 + threadIdx.x;
    float cand = 0.f;
    if (e < E){
        int s = src[e], d = dst[e];
        float c0 = pos[s*2]   - pos[d*2];
        float c1 = pos[s*2+1] - pos[d*2+1];
        cand = fmaxf(fabsf(c0), fabsf(c1));
    }
    __shared__ float sm[256];
    sm[threadIdx.x] = cand; __syncthreads();
    for (int o = 128; o > 0; o >>= 1){
        if (threadIdx.x < o) sm[threadIdx.x] = fmaxf(sm[threadIdx.x], sm[threadIdx.x + o]);
        __syncthreads();
    }
    if (threadIdx.x == 0 && sm[0] > 0.f) atomicMax(amax, __float_as_uint(sm[0]));
}

// ---------------- conv1: aggregate (Fin=1) ----------------
__global__ void conv1_edge_k(const float* __restrict__ x, const float* __restrict__ pos,
                             const int* __restrict__ src, const int* __restrict__ dst, int E,
                             const unsigned* __restrict__ amaxp,
                             float* __restrict__ acc, float* __restrict__ deg){
    int e = blockIdx.x * 256 + threadIdx.x;
    if (e >= E) return;
    int s = src[e], d = dst[e];
    float am = __uint_as_float(*amaxp);
    float c0 = pos[s*2]   - pos[d*2];
    float c1 = pos[s*2+1] - pos[d*2+1];
    int kks[4]; float wsp[4];
    spline2(c0, c1, am, kks, wsp);
    float xv = x[s];
    #pragma unroll
    for (int c = 0; c < 4; c++) atomicAdd(&acc[(size_t)d*25 + kks[c]], wsp[c] * xv);
    atomicAdd(&deg[d], 1.f);
}

__global__ void conv1_node_k(const float* __restrict__ acc, const float* __restrict__ deg,
                             const float* __restrict__ x, const float* __restrict__ W1,
                             const float* __restrict__ r1, const float* __restrict__ b1,
                             int N, float* __restrict__ out){
    int gid = blockIdx.x * 256 + threadIdx.x;
    int i = gid >> 5, o = gid & 31;
    if (i >= N) return;
    float sum = 0.f;
    #pragma unroll
    for (int k = 0; k < 25; k++) sum += acc[(size_t)i*25 + k] * W1[k*32 + o];
    float v = sum / fmaxf(deg[i], 1.f) + x[i] * r1[o] + b1[o];
    out[(size_t)i*32 + o] = eluf(v);
}

// ---------------- generic pooling ----------------
template<int LOGF>
__global__ void pool_node_k(const float* __restrict__ x, const float* __restrict__ pos,
                            const float* __restrict__ valid, int n, float size, int G, int npg,
                            int* __restrict__ cl, unsigned* __restrict__ pxenc,
                            float* __restrict__ cnt, float* __restrict__ possum){
    const int F = 1 << LOGF;
    int gid = blockIdx.x * 256 + threadIdx.x;
    int i = gid >> LOGF, f = gid & (F - 1);
    if (i >= n) return;
    float p0 = pos[i*2], p1 = pos[i*2+1];
    int c0 = min(max((int)floorf(p0 / size), 0), G - 1);
    int c1 = min(max((int)floorf(p1 / size), 0), G - 1);
    int b = i / npg;
    int c = b * G * G + c1 * G + c0;
    if (f == 0) cl[i] = c;
    float vld = valid ? valid[i] : 1.f;
    if (vld > 0.f){
        atomicMax(&pxenc[(size_t)c*F + f], fenc(x[(size_t)i*F + f]));
        if (f == 0){
            atomicAdd(&cnt[c], 1.f);
            atomicAdd(&possum[c*2],     p0);
            atomicAdd(&possum[c*2 + 1], p1);
        }
    }
}

template<int LOGF>
__global__ void pool_fin_k(unsigned* __restrict__ pxenc, const float* __restrict__ cnt,
                           float* __restrict__ possum, float* __restrict__ sval, int S){
    const int F = 1 << LOGF;
    int gid = blockIdx.x * 256 + threadIdx.x;
    int s = gid >> LOGF, f = gid & (F - 1);
    if (s >= S) return;
    float c = cnt[s];
    float v = (c > 0.f) ? fdec(pxenc[(size_t)s*F + f]) : 0.f;
    ((float*)pxenc)[(size_t)s*F + f] = v;
    if (f == 0){
        float m = fmaxf(c, 1.f);
        possum[s*2]     /= m;
        possum[s*2 + 1] /= m;
        sval[s] = (c > 0.f) ? 1.f : 0.f;
    }
}

// ---------------- edge remap + dedup ----------------
__global__ void dedup_a_k(const int* __restrict__ esrc_in, const int* __restrict__ edst_in,
                          const int* __restrict__ clmap, const unsigned char* __restrict__ maskin,
                          int E, int GG, int* __restrict__ esrc_out, int* __restrict__ edst_out,
                          unsigned* __restrict__ pairmark){
    int e = blockIdx.x * 256 + threadIdx.x;
    if (e >= E) return;
    int a = clmap[esrc_in[e]], b = clmap[edst_in[e]];
    esrc_out[e] = a; edst_out[e] = b;
    bool m = (maskin ? (maskin[e] != 0) : true) && (a != b);
    if (m){
        int g = a / GG;
        unsigned key = (unsigned)((size_t)g * GG * GG + (a - g * GG) * GG + (b - g * GG));
        atomicMin(&pairmark[key], (unsigned)e);
    }
}

__global__ void dedup_b_k(const int* __restrict__ esrc, const int* __restrict__ edst,
                          const unsigned char* __restrict__ maskin, const unsigned* __restrict__ pairmark,
                          const float* __restrict__ ppos, int E, int GG,
                          unsigned char* __restrict__ kf, float* __restrict__ deg,
                          unsigned* __restrict__ amax){
    int e = blockIdx.x * 256 + threadIdx.x;
    float cand = 0.f;
    if (e < E){
        int a = esrc[e], b = edst[e];
        bool m = (maskin ? (maskin[e] != 0) : true) && (a != b);
        bool kept = false;
        if (m){
            int g = a / GG;
            unsigned key = (unsigned)((size_t)g * GG * GG + (a - g * GG) * GG + (b - g * GG));
            kept = (pairmark[key] == (unsigned)e);
        }
        kf[e] = kept ? 1 : 0;
        if (kept){
            float c0 = ppos[a*2]   - ppos[b*2];
            float c1 = ppos[a*2+1] - ppos[b*2+1];
            cand = fmaxf(fabsf(c0), fabsf(c1));
            atomicAdd(&deg[b], 1.f);
        }
    }
    __shared__ float sm[256];
    sm[threadIdx.x] = cand; __syncthreads();
    for (int o = 128; o > 0; o >>= 1){
        if (threadIdx.x < o) sm[threadIdx.x] = fmaxf(sm[threadIdx.x], sm[threadIdx.x + o]);
        __syncthreads();
    }
    if (threadIdx.x == 0 && sm[0] > 0.f) atomicMax(amax, __float_as_uint(sm[0]));
}

// ---------------- CSR build: exclusive scan of deg + fill ----------------
__global__ void scan_k(const float* __restrict__ deg, int n,
                       int* __restrict__ rowptr, int* __restrict__ cursor){
    __shared__ int wt[16];
    __shared__ int wo[17];
    __shared__ int carry;
    int t = threadIdx.x, lane = t & 63, wid = t >> 6;
    if (t == 0) carry = 0;
    __syncthreads();
    for (int base = 0; base < n; base += 1024){
        int i = base + t;
        int v = (i < n) ? (int)deg[i] : 0;
        int incl = v;
        #pragma unroll
        for (int o = 1; o < 64; o <<= 1){
            int u = __shfl_up(incl, o, 64);
            if (lane >= o) incl += u;
        }
        if (lane == 63) wt[wid] = incl;
        __syncthreads();
        if (t == 0){
            int run = 0;
            #pragma unroll
            for (int wv = 0; wv < 16; wv++){ wo[wv] = run; run += wt[wv]; }
            wo[16] = run;
        }
        __syncthreads();
        int ex = incl - v + wo[wid] + carry;
        if (i < n){ rowptr[i] = ex; cursor[i] = ex; }
        __syncthreads();
        if (t == 0) carry += wo[16];
        __syncthreads();
    }
    if (t == 0) rowptr[n] = carry;
}

__global__ void csr_fill_k(const unsigned char* __restrict__ kf, const int* __restrict__ edst,
                           int E, int* __restrict__ cursor, int* __restrict__ elist){
    int e = blockIdx.x * 256 + threadIdx.x;
    if (e >= E) return;
    if (!kf[e]) return;
    int idx = atomicAdd(&cursor[edst[e]], 1);
    elist[idx] = e;
}

// ---------------- conv2/conv3: CSR gather into LDS basis acc + fused transform ----------------
// 4 dst-nodes per 256-block, 64 lanes per node. acc[25][FIN] per node in LDS.
// FIN=32: two edges per iteration (half-wave each) into two separate buffers (no LDS race).
template<int FIN>
__global__ __launch_bounds__(256) void conv_csr_k(
        const float* __restrict__ x, const float* __restrict__ ppos,
        const int* __restrict__ esrc, const int* __restrict__ elist,
        const int* __restrict__ rowptr, const float* __restrict__ W,
        const float* __restrict__ root, const float* __restrict__ bias,
        const unsigned* __restrict__ amaxp, int n, float* __restrict__ out){
    constexpr int EPB = (FIN == 32) ? 2 : 1;       // edges per iteration
    constexpr int ACC = 25 * FIN;
    __shared__ float acc[4 * EPB * ACC];           // 25.6 KB either way
    int g = threadIdx.x >> 6, lane = threadIdx.x & 63;
    int node = blockIdx.x * 4 + g;
    float* accg = acc + g * EPB * ACC;

    for (int i = threadIdx.x; i < 4 * EPB * ACC; i += 256) acc[i] = 0.f;
    __syncthreads();

    int row0 = 0, row1 = 0;
    if (node < n){
        row0 = rowptr[node]; row1 = rowptr[node + 1];
        float am = __uint_as_float(*amaxp);
        float pd0 = ppos[node*2], pd1 = ppos[node*2 + 1];
        int ebuf = (EPB == 2) ? (lane >> 5) : 0;
        int f = lane & (FIN - 1);
        float* ab = accg + ebuf * ACC;
        for (int i = row0 + ebuf; i < row1; i += EPB){
            int e = elist[i];
            int a = esrc[e];
            float c0 = ppos[a*2]     - pd0;
            float c1 = ppos[a*2 + 1] - pd1;
            int kks[4]; float wsp[4];
            spline2(c0, c1, am, kks, wsp);
            float xv = x[(size_t)a * FIN + f];
            #pragma unroll
            for (int c = 0; c < 4; c++) ab[kks[c] * FIN + f] += wsp[c] * xv;
        }
    }
    __syncthreads();

    if (node >= n) return;
    float sum = 0.f;
    #pragma unroll 8
    for (int j = 0; j < ACC; j++){
        float av = (EPB == 2) ? (accg[j] + accg[ACC + j]) : accg[j];
        sum += av * W[(size_t)j * 64 + lane];
    }
    float degv = (float)max(row1 - row0, 1);
    float r = 0.f;
    #pragma unroll 8
    for (int f2 = 0; f2 < FIN; f2++) r += x[(size_t)node * FIN + f2] * root[(size_t)f2 * 64 + lane];
    float v = sum / degv + r + bias[lane];
    out[(size_t)node * 64 + lane] = eluf(v);
}

// ---------------- MLP head + log_softmax ----------------
__global__ void mlp_k(const float* __restrict__ px, const float* __restrict__ fw1,
                      const float* __restrict__ fb1, const float* __restrict__ fw2,
                      const float* __restrict__ fb2, float* __restrict__ out){
    __shared__ float xr[256];
    __shared__ float h[128];
    __shared__ float lg[10];
    __shared__ float lse;
    int g = blockIdx.x, t = threadIdx.x;
    xr[t]       = px[(size_t)g*256 + t];
    xr[t + 128] = px[(size_t)g*256 + 128 + t];
    __syncthreads();
    float s = fb1[t];
    const float* wrow = fw1 + (size_t)t * 256;
    #pragma unroll 8
    for (int i = 0; i < 256; i++) s += xr[i] * wrow[i];
    h[t] = eluf(s);
    __syncthreads();
    if (t < 10){
        float s2 = fb2[t];
        const float* w2 = fw2 + (size_t)t * 128;
        for (int j = 0; j < 128; j++) s2 += h[j] * w2[j];
        lg[t] = s2;
    }
    __syncthreads();
    if (t == 0){
        float m = lg[0];
        for (int c = 1; c < 10; c++) m = fmaxf(m, lg[c]);
        float se = 0.f;
        for (int c = 0; c < 10; c++) se += expf(lg[c] - m);
        lse = m + logf(se);
    }
    __syncthreads();
    if (t < 10) out[(size_t)g*10 + t] = lg[t] - lse;
}

extern "C" void kernel_launch(void* const* d_in, const int* in_sizes, int n_in,
                              void* d_out, int out_size, void* d_ws, size_t ws_size,
                              hipStream_t stream) {
    const float* x   = (const float*)d_in[0];
    const float* pos = (const float*)d_in[1];
    const int*   src = (const int*)d_in[2];
    const int*   dst = (const int*)d_in[3];
    const float* W1  = (const float*)d_in[4];
    const float* r1  = (const float*)d_in[5];
    const float* b1  = (const float*)d_in[6];
    const float* W2  = (const float*)d_in[7];
    const float* r2  = (const float*)d_in[8];
    const float* b2  = (const float*)d_in[9];
    const float* W3  = (const float*)d_in[10];
    const float* r3  = (const float*)d_in[11];
    const float* b3  = (const float*)d_in[12];
    const float* fw1 = (const float*)d_in[13];
    const float* fb1 = (const float*)d_in[14];
    const float* fw2 = (const float*)d_in[15];
    const float* fb2 = (const float*)d_in[16];
    float* out = (float*)d_out;

    const int N  = in_sizes[0];
    const int E  = in_sizes[2];
    const int B  = N / NPG;
    const int S1 = B * 36;
    const int S2 = B * 25;
    const int B4 = B * 4;

    float* w = (float*)d_ws;
    size_t off = 0;
    auto alloc = [&](size_t nelem){ size_t o = off; off += (nelem + 63) & ~(size_t)63; return o; };

    // zero-init region
    size_t o_scal = alloc(4);                 // amax0, amax1, amax2 (uint bits of nonneg floats)
    size_t o_acc1 = alloc((size_t)N * 25);
    size_t o_deg1 = alloc(N);
    size_t o_cnt1 = alloc(S1);
    size_t o_pp1  = alloc((size_t)S1 * 2);
    size_t o_px1  = alloc((size_t)S1 * 32);
    size_t o_deg2 = alloc(S1);
    size_t o_cnt2 = alloc(S2);
    size_t o_pp2  = alloc((size_t)S2 * 2);
    size_t o_px2  = alloc((size_t)S2 * 64);
    size_t o_deg3 = alloc(S2);
    size_t o_cnt3 = alloc(B4);
    size_t o_pp3  = alloc((size_t)B4 * 2);
    size_t o_px3  = alloc((size_t)B4 * 64);
    size_t zeroEnd = off;
    // 0xFF-init region (pair markers, atomicMin with UINT_MAX init)
    size_t o_pm1 = alloc((size_t)B * 36 * 36);
    size_t o_pm2 = alloc((size_t)B * 25 * 25);
    size_t ffEnd = off;
    // no-init region (fully written before read)
    size_t o_out1  = alloc((size_t)N * 32);
    size_t o_out2  = alloc((size_t)S1 * 64);
    size_t o_out3  = alloc((size_t)S2 * 64);
    size_t o_cl1   = alloc(N);
    size_t o_sv1   = alloc(S1);
    size_t o_es1   = alloc(E);
    size_t o_ed1   = alloc(E);
    size_t o_kf1   = alloc((E + 3) / 4);
    size_t o_cl2   = alloc(S1);
    size_t o_sv2   = alloc(S2);
    size_t o_es2   = alloc(E);
    size_t o_ed2   = alloc(E);
    size_t o_kf2   = alloc((E + 3) / 4);
    size_t o_cl3   = alloc(S2);
    size_t o_sv3   = alloc(B4);
    size_t o_rp2   = alloc(S1 + 1);
    size_t o_cur2  = alloc(S1);
    size_t o_el2   = alloc(E);
    size_t o_rp3   = alloc(S2 + 1);
    size_t o_cur3  = alloc(S2);
    size_t o_el3   = alloc(E);

    hipMemsetAsync(w, 0, zeroEnd * sizeof(float), stream);
    hipMemsetAsync((char*)d_ws + zeroEnd * sizeof(float), 0xFF, (ffEnd - zeroEnd) * sizeof(float), stream);

    unsigned* scal = (unsigned*)(w + o_scal);
    auto nb = [](long long t){ return (unsigned)((t + 255) / 256); };
    auto nb4 = [](long long t){ return (unsigned)((t + 3) / 4); };

    // stage 1: conv1 on original graph
    amax0_k<<<nb(E), 256, 0, stream>>>(pos, src, dst, E, scal + 0);
    conv1_edge_k<<<nb(E), 256, 0, stream>>>(x, pos, src, dst, E, scal + 0, w + o_acc1, w + o_deg1);
    conv1_node_k<<<nb((long long)N * 32), 256, 0, stream>>>(w + o_acc1, w + o_deg1, x, W1, r1, b1, N, w + o_out1);

    // pool 1 (size=5, G=6)
    pool_node_k<5><<<nb((long long)N * 32), 256, 0, stream>>>(
        w + o_out1, pos, nullptr, N, 5.f, 6, NPG,
        (int*)(w + o_cl1), (unsigned*)(w + o_px1), w + o_cnt1, w + o_pp1);
    pool_fin_k<5><<<nb((long long)S1 * 32), 256, 0, stream>>>(
        (unsigned*)(w + o_px1), w + o_cnt1, w + o_pp1, w + o_sv1, S1);
    dedup_a_k<<<nb(E), 256, 0, stream>>>(src, dst, (int*)(w + o_cl1), nullptr, E, 36,
                                         (int*)(w + o_es1), (int*)(w + o_ed1), (unsigned*)(w + o_pm1));
    dedup_b_k<<<nb(E), 256, 0, stream>>>((int*)(w + o_es1), (int*)(w + o_ed1), nullptr,
                                         (unsigned*)(w + o_pm1), w + o_pp1, E, 36,
                                         (unsigned char*)(w + o_kf1), w + o_deg2, scal + 1);

    // conv2 (Fin=32 -> 64) on S1 clusters: CSR + fused gather/transform
    scan_k<<<1, 1024, 0, stream>>>(w + o_deg2, S1, (int*)(w + o_rp2), (int*)(w + o_cur2));
    csr_fill_k<<<nb(E), 256, 0, stream>>>((unsigned char*)(w + o_kf1), (int*)(w + o_ed1), E,
                                          (int*)(w + o_cur2), (int*)(w + o_el2));
    conv_csr_k<32><<<nb4(S1), 256, 0, stream>>>(
        w + o_px1, w + o_pp1, (int*)(w + o_es1), (int*)(w + o_el2), (int*)(w + o_rp2),
        W2, r2, b2, scal + 1, S1, w + o_out2);

    // pool 2 (size=7, G=5)
    pool_node_k<6><<<nb((long long)S1 * 64), 256, 0, stream>>>(
        w + o_out2, w + o_pp1, w + o_sv1, S1, 7.f, 5, 36,
        (int*)(w + o_cl2), (unsigned*)(w + o_px2), w + o_cnt2, w + o_pp2);
    pool_fin_k<6><<<nb((long long)S2 * 64), 256, 0, stream>>>(
        (unsigned*)(w + o_px2), w + o_cnt2, w + o_pp2, w + o_sv2, S2);
    dedup_a_k<<<nb(E), 256, 0, stream>>>((int*)(w + o_es1), (int*)(w + o_ed1), (int*)(w + o_cl2),
                                         (unsigned char*)(w + o_kf1), E, 25,
                                         (int*)(w + o_es2), (int*)(w + o_ed2), (unsigned*)(w + o_pm2));
    dedup_b_k<<<nb(E), 256, 0, stream>>>((int*)(w + o_es2), (int*)(w + o_ed2),
                                         (unsigned char*)(w + o_kf1), (unsigned*)(w + o_pm2),
                                         w + o_pp2, E, 25,
                                         (unsigned char*)(w + o_kf2), w + o_deg3, scal + 2);

    // conv3 (Fin=64 -> 64) on S2 clusters: CSR + fused gather/transform
    scan_k<<<1, 1024, 0, stream>>>(w + o_deg3, S2, (int*)(w + o_rp3), (int*)(w + o_cur3));
    csr_fill_k<<<nb(E), 256, 0, stream>>>((unsigned char*)(w + o_kf2), (int*)(w + o_ed2), E,
                                          (int*)(w + o_cur3), (int*)(w + o_el3));
    conv_csr_k<64><<<nb4(S2), 256, 0, stream>>>(
        w + o_px2, w + o_pp2, (int*)(w + o_es2), (int*)(w + o_el3), (int*)(w + o_rp3),
        W3, r3, b3, scal + 2, S2, w + o_out3);

    // final max_pool_x (size=14, G=2) — reuse generic pooling; pos/cl/sval outputs unused
    pool_node_k<6><<<nb((long long)S2 * 64), 256, 0, stream>>>(
        w + o_out3, w + o_pp2, w + o_sv2, S2, 14.f, 2, 25,
        (int*)(w + o_cl3), (unsigned*)(w + o_px3), w + o_cnt3, w + o_pp3);
    pool_fin_k<6><<<nb((long long)B4 * 64), 256, 0, stream>>>(
        (unsigned*)(w + o_px3), w + o_cnt3, w + o_pp3, w + o_sv3, B4);

    // MLP head + log_softmax
    mlp_k<<<B, 128, 0, stream>>>(w + o_px3, fw1, fb1, fw2, fb2, out);
}